// Round 2
// baseline (131.794 us; speedup 1.0000x reference)
//
#include <hip/hip_runtime.h>

#define NUSR 8192
#define HDIM 256

typedef __attribute__((ext_vector_type(8))) __bf16 bf16x8;
typedef __attribute__((ext_vector_type(4))) float f32x4;

union frag_u { bf16x8 v; unsigned short u[8]; };

// f32 -> bf16 round-to-nearest-even (finite inputs; no NaN path needed)
__device__ __forceinline__ unsigned short f2bf(float f) {
  unsigned u = __builtin_bit_cast(unsigned, f);
  u += 0x7FFFu + ((u >> 16) & 1u);
  return (unsigned short)(u >> 16);
}

__device__ __forceinline__ float sigmoidf_fast(float x) {
  float e = __builtin_amdgcn_exp2f(x * -1.44269504088896340736f);
  return __builtin_amdgcn_rcpf(1.0f + e);
}

// ---------------------------------------------------------------------------
// k1: Pbf[j][s] = bf16( sum_t yb[j][t]*W[s][t] + b[s] )
// Both operands have contiguous reduction index t -> no transpose staging.
// grid 256 blocks x 256 thr: block = 32 yb-rows; wave w = 64 proj-cols.
// ---------------------------------------------------------------------------
__global__ __launch_bounds__(256) void k1_proj(
    const float* __restrict__ yb, const float* __restrict__ W,
    const float* __restrict__ bvec, unsigned short* __restrict__ Pbf)
{
  const int tid  = threadIdx.x;
  const int lane = tid & 63;
  const int w    = tid >> 6;
  const int quad = lane >> 4;
  const int l15  = lane & 15;
  const int rb   = blockIdx.x * 32;

  // A-frags: yb rows rb..rb+31, fp32 loaded + converted in-register
  frag_u A[2][8];
#pragma unroll
  for (int h = 0; h < 2; ++h) {
    const float* src = yb + (size_t)(rb + h * 16 + l15) * HDIM;
#pragma unroll
    for (int kb = 0; kb < 8; ++kb) {
      float4 v0 = *(const float4*)&src[kb * 32 + quad * 8];
      float4 v1 = *(const float4*)&src[kb * 32 + quad * 8 + 4];
      A[h][kb].u[0] = f2bf(v0.x); A[h][kb].u[1] = f2bf(v0.y);
      A[h][kb].u[2] = f2bf(v0.z); A[h][kb].u[3] = f2bf(v0.w);
      A[h][kb].u[4] = f2bf(v1.x); A[h][kb].u[5] = f2bf(v1.y);
      A[h][kb].u[6] = f2bf(v1.z); A[h][kb].u[7] = f2bf(v1.w);
    }
  }

#pragma unroll
  for (int tt = 0; tt < 4; ++tt) {
    const int scol = w * 64 + tt * 16 + l15;
    const float* wrow = W + (size_t)scol * HDIM;
    f32x4 a0 = {0.f,0.f,0.f,0.f}, a1 = {0.f,0.f,0.f,0.f};
#pragma unroll
    for (int kb = 0; kb < 8; ++kb) {
      float4 v0 = *(const float4*)&wrow[kb * 32 + quad * 8];
      float4 v1 = *(const float4*)&wrow[kb * 32 + quad * 8 + 4];
      frag_u B;
      B.u[0] = f2bf(v0.x); B.u[1] = f2bf(v0.y);
      B.u[2] = f2bf(v0.z); B.u[3] = f2bf(v0.w);
      B.u[4] = f2bf(v1.x); B.u[5] = f2bf(v1.y);
      B.u[6] = f2bf(v1.z); B.u[7] = f2bf(v1.w);
      a0 = __builtin_amdgcn_mfma_f32_16x16x32_bf16(A[0][kb].v, B.v, a0, 0, 0, 0);
      a1 = __builtin_amdgcn_mfma_f32_16x16x32_bf16(A[1][kb].v, B.v, a1, 0, 0, 0);
    }
    const float bcol = bvec[scol];
    // C/D layout: col = lane&15 (s-dim), row = quad*4 + r (j-dim)
#pragma unroll
    for (int r = 0; r < 4; ++r) {
      Pbf[(size_t)(rb + quad * 4 + r) * HDIM + scol]      = f2bf(a0[r] + bcol);
      Pbf[(size_t)(rb + 16 + quad * 4 + r) * HDIM + scol] = f2bf(a1[r] + bcol);
    }
  }
}

// ---------------------------------------------------------------------------
// k2: s[i] += sum_j sigmoid( ya[i] . proj[j] )  over this block's col range
// grid (64,16): x = 128-row band (4 waves x 32 rows), y = 512-col chunk
// 1024 blocks -> 4 blocks/CU (LDS-capped), 16 waves/CU target
// ---------------------------------------------------------------------------
__global__ __launch_bounds__(256) void k2_score(
    const float* __restrict__ ya, const unsigned short* __restrict__ Pbf,
    float* __restrict__ svec)
{
  __shared__ __align__(16) unsigned short bs[64 * 264]; // proj tile [col][k], stride 264
  const int tid  = threadIdx.x;
  const int lane = tid & 63;
  const int w    = tid >> 6;
  const int quad = lane >> 4;
  const int l15  = lane & 15;
  const int rbase = blockIdx.x * 128 + w * 32;
  const int cbase = blockIdx.y * 512;

  // A-frags: 32 ya rows, fp32 loaded + converted in-register (64 VGPRs held)
  frag_u A[2][8];
#pragma unroll
  for (int h = 0; h < 2; ++h) {
    const float* src = ya + (size_t)(rbase + h * 16 + l15) * HDIM;
#pragma unroll
    for (int kb = 0; kb < 8; ++kb) {
      float4 v0 = *(const float4*)&src[kb * 32 + quad * 8];
      float4 v1 = *(const float4*)&src[kb * 32 + quad * 8 + 4];
      A[h][kb].u[0] = f2bf(v0.x); A[h][kb].u[1] = f2bf(v0.y);
      A[h][kb].u[2] = f2bf(v0.z); A[h][kb].u[3] = f2bf(v0.w);
      A[h][kb].u[4] = f2bf(v1.x); A[h][kb].u[5] = f2bf(v1.y);
      A[h][kb].u[6] = f2bf(v1.z); A[h][kb].u[7] = f2bf(v1.w);
    }
  }

  float rs[2][4] = {{0.f,0.f,0.f,0.f},{0.f,0.f,0.f,0.f}};

  for (int st = 0; st < 8; ++st) {
    __syncthreads(); // previous tile's reads complete before overwrite
    {
      const uint4* src = (const uint4*)(Pbf + (size_t)(cbase + st * 64) * HDIM);
#pragma unroll
      for (int p = 0; p < 8; ++p) {
        int lin = p * 256 + tid;
        int row = lin >> 5, ch = lin & 31;
        *(uint4*)&bs[row * 264 + ch * 8] = src[row * 32 + ch];
      }
    }
    __syncthreads();
#pragma unroll
    for (int tt = 0; tt < 4; ++tt) {
      f32x4 a0 = {0.f,0.f,0.f,0.f}, a1 = {0.f,0.f,0.f,0.f};
#pragma unroll
      for (int kb = 0; kb < 8; ++kb) {
        bf16x8 bfrag = *(const bf16x8*)&bs[(tt * 16 + l15) * 264 + kb * 32 + quad * 8];
        a0 = __builtin_amdgcn_mfma_f32_16x16x32_bf16(A[0][kb].v, bfrag, a0, 0, 0, 0);
        a1 = __builtin_amdgcn_mfma_f32_16x16x32_bf16(A[1][kb].v, bfrag, a1, 0, 0, 0);
      }
#pragma unroll
      for (int r = 0; r < 4; ++r) {
        rs[0][r] += sigmoidf_fast(a0[r]);
        rs[1][r] += sigmoidf_fast(a1[r]);
      }
    }
  }

  // reduce over the 16 col-lanes within each quad group
#pragma unroll
  for (int off = 1; off < 16; off <<= 1) {
#pragma unroll
    for (int h = 0; h < 2; ++h)
#pragma unroll
      for (int r = 0; r < 4; ++r)
        rs[h][r] += __shfl_xor(rs[h][r], off, 64);
  }
  if (l15 == 0) {
#pragma unroll
    for (int h = 0; h < 2; ++h)
#pragma unroll
      for (int r = 0; r < 4; ++r)
        atomicAdd(&svec[rbase + h * 16 + quad * 4 + r], rs[h][r]);
  }
}

// ---------------------------------------------------------------------------
// k3: out[i][k] = s[i] / 256
// ---------------------------------------------------------------------------
__global__ __launch_bounds__(256) void k3_bcast(
    const float* __restrict__ svec, float* __restrict__ out)
{
  int idx = blockIdx.x * 256 + threadIdx.x; // float4 index
  int row = idx >> 6;                        // 64 float4 per row
  float v = svec[row] * (1.0f / 256.0f);
  float4 o = {v, v, v, v};
  ((float4*)out)[idx] = o;
}

extern "C" void kernel_launch(void* const* d_in, const int* in_sizes, int n_in,
                              void* d_out, int out_size, void* d_ws, size_t ws_size,
                              hipStream_t stream) {
  (void)in_sizes; (void)n_in; (void)out_size;
  const float* ya = (const float*)d_in[0];
  const float* yb = (const float*)d_in[1];
  const float* W  = (const float*)d_in[2];
  const float* bv = (const float*)d_in[3];
  float* out = (float*)d_out;

  char* ws = (char*)d_ws;
  unsigned short* Pbf;
  float* svec;
  const size_t need = (4ull << 20) + (32ull << 10);
  if (ws_size >= need) {
    Pbf  = (unsigned short*)ws;
    svec = (float*)(ws + (4 << 20));
  } else {
    // fallback: proj scratch in d_out (fully rewritten by k3 after k2 done)
    Pbf  = (unsigned short*)d_out;
    svec = (float*)ws; // 32 KB
  }

  hipMemsetAsync(svec, 0, NUSR * sizeof(float), stream);
  k1_proj<<<256, 256, 0, stream>>>(yb, W, bv, Pbf);
  k2_score<<<dim3(64, 16), 256, 0, stream>>>(ya, Pbf, svec);
  k3_bcast<<<2048, 256, 0, stream>>>(svec, out);
}